// Round 1
// 2642.580 us; speedup vs baseline: 1.1775x; 1.1775x over previous
//
#include <hip/hip_runtime.h>
#include <cstdint>
#include <cstddef>

#define B_    128
#define P_    196
#define ENC_  2048
#define ATT_  512
#define DEC_  512
#define EMB_  512
#define V_    30000
#define VPAD_ 30080                  /* 235*128, padded rows of WfcT */
#define L_    22
#define T_    21
#define KGATE (EMB_ + ENC_ + DEC_)   /* 3072 */
#define NGATE (4*DEC_)               /* 2048 */
#define KS    8                      /* split-K slices for per-step GEMMs */
#define LDSK  40                     /* padded LDS k-stride (bf16 elems) */

typedef unsigned short u16;
typedef unsigned int   u32;
typedef float f32x4 __attribute__((ext_vector_type(4)));
typedef short s16x8 __attribute__((ext_vector_type(8)));

__device__ __forceinline__ u16 f2bf(float f){
  u32 u = __float_as_uint(f);
  u = (u + 0x7fffu + ((u >> 16) & 1u)) >> 16;
  return (u16)u;
}
__device__ __forceinline__ float bf2f(u16 h){
  return __uint_as_float(((u32)h) << 16);
}

__device__ __forceinline__ void gload_lds16(const u16* g, u16* l){
  __builtin_amdgcn_global_load_lds(
      (const __attribute__((address_space(1))) void*)g,
      (__attribute__((address_space(3))) void*)l, 16, 0, 0);
}

// ---------------------------------------------------------------------------
// High-throughput bf16 GEMM, both operands K-contiguous:
//   C(MxN) = A(M x K, row-major) @ Bt(N x K, row-major)^T
// 128x128 tile, BK=32, 4 waves (2x2, each wave 64x64 = acc[4][4]).
// Staging: global_load_lds 16B, linear LDS dest + XOR-swizzled global source
// (chunk ^= (row>>1)&3) so swizzled ds_read_b128 frag reads are conflict-free.
// MODE 0: bf16 out + bias (row-major, ldc=N), for attn1. grid (N/128, M/128)
// MODE 2: fc epilogue: fp32 scattered to (b,t,v), bias + mask, col<N guard.
//         grid (M/128, N-tiles) -- M-major so consecutive blocks reuse B panel.
// ---------------------------------------------------------------------------
template<int MODE>
__global__ __launch_bounds__(256)
void gemm_bt(const u16* __restrict__ A,
             const u16* __restrict__ Bt,
             int N, int K,
             const float* __restrict__ bias,
             u16* __restrict__ outb,
             float* __restrict__ outp,
             const int* __restrict__ declens)
{
  __shared__ __align__(16) u16 As[128*32];
  __shared__ __align__(16) u16 Bs[128*32];
  __shared__ __align__(16) float Cs[32*132];

  const int tid = threadIdx.x;
  const int bxn = (MODE == 2) ? blockIdx.y : blockIdx.x;
  const int bym = (MODE == 2) ? blockIdx.x : blockIdx.y;
  const int nt = bxn * 128;
  const size_t mt = (size_t)bym * 128;

  const int wv = tid >> 6;
  const int ln = tid & 63;
  const int lm = ln & 15;
  const int qd = ln >> 4;
  const int wr = wv >> 1;
  const int wc = wv & 1;

  f32x4 acc[4][4];
  #pragma unroll
  for (int i=0;i<4;i++)
    #pragma unroll
    for (int j=0;j<4;j++) acc[i][j] = f32x4{0.f,0.f,0.f,0.f};

  // staging: 512 chunks of 16B per tile; thread handles chunks tid and 256+tid.
  // LDS dest linear (wave-uniform base + lane*16); source column XOR-swizzled.
  const int c0 = tid, c1 = 256 + tid;
  const int ar0 = c0 >> 2, ac0 = (((c0 & 3) ^ ((ar0 >> 1) & 3)) * 8);
  const int ar1 = c1 >> 2, ac1 = (((c1 & 3) ^ ((ar1 >> 1) & 3)) * 8);
  const u16* Ab0 = A  + (mt + ar0) * (size_t)K + ac0;
  const u16* Ab1 = A  + (mt + ar1) * (size_t)K + ac1;
  const u16* Bb0 = Bt + ((size_t)nt + ar0) * (size_t)K + ac0;
  const u16* Bb1 = Bt + ((size_t)nt + ar1) * (size_t)K + ac1;
  u16* lA0 = As + (size_t)c0 * 8;
  u16* lA1 = As + (size_t)c1 * 8;
  u16* lB0 = Bs + (size_t)c0 * 8;
  u16* lB1 = Bs + (size_t)c1 * 8;

  // fragment read offsets (swizzled to match source permutation)
  int aoff[4], boff[4];
  #pragma unroll
  for (int i=0;i<4;i++){
    int ra = wr*64 + i*16 + lm;
    aoff[i] = ra*32 + ((qd ^ ((ra >> 1) & 3)) * 8);
    int rb = wc*64 + i*16 + lm;
    boff[i] = rb*32 + ((qd ^ ((rb >> 1) & 3)) * 8);
  }

  for (int kc = 0; kc < K; kc += 32){
    gload_lds16(Ab0 + kc, lA0);
    gload_lds16(Ab1 + kc, lA1);
    gload_lds16(Bb0 + kc, lB0);
    gload_lds16(Bb1 + kc, lB1);
    __syncthreads();
    s16x8 af[4], bfr[4];
    #pragma unroll
    for (int i=0;i<4;i++) af[i]  = *reinterpret_cast<const s16x8*>(As + aoff[i]);
    #pragma unroll
    for (int i=0;i<4;i++) bfr[i] = *reinterpret_cast<const s16x8*>(Bs + boff[i]);
    #pragma unroll
    for (int i=0;i<4;i++)
      #pragma unroll
      for (int j=0;j<4;j++)
        acc[i][j] = __builtin_amdgcn_mfma_f32_16x16x32_bf16(af[i], bfr[j], acc[i][j], 0, 0, 0);
    __syncthreads();
  }

  // epilogue: 4 slices of 32 rows x 128 cols staged through Cs for coalescing
  #pragma unroll
  for (int mi=0; mi<4; mi++){
    const int lrb = wr*16 + qd*4;
    #pragma unroll
    for (int ni=0; ni<4; ni++)
      #pragma unroll
      for (int rr=0; rr<4; rr++)
        Cs[(lrb+rr)*132 + wc*64 + ni*16 + lm] = acc[mi][ni][rr];
    __syncthreads();
    const int er = tid >> 3;           // 0..31 local row
    const int ec = (tid & 7) * 16;     // col base, 8 threads span a row
    const size_t grow = mt + (size_t)(er >> 4)*64 + mi*16 + (er & 15);
    const float* cr = Cs + er*132 + ec;
    if (MODE == 0){
      __align__(16) u16 pk[16];
      #pragma unroll
      for (int j=0;j<16;j++) pk[j] = f2bf(cr[j] + bias[nt + ec + j]);
      uint4* dst = reinterpret_cast<uint4*>(outb + grow*(size_t)N + nt + ec);
      dst[0] = *reinterpret_cast<uint4*>(pk);
      dst[1] = *reinterpret_cast<uint4*>(pk + 8);
    } else {
      const int ti = (int)(grow >> 7);
      const int bb = (int)(grow & 127);
      const bool act = ti < declens[bb];
      float* dst = outp + ((size_t)bb*T_ + ti)*(size_t)V_ + nt + ec;
      if (nt + 128 <= N){
        #pragma unroll
        for (int j=0;j<4;j++){
          float4 v;
          v.x = act ? cr[4*j+0] + bias[nt+ec+4*j+0] : 0.f;
          v.y = act ? cr[4*j+1] + bias[nt+ec+4*j+1] : 0.f;
          v.z = act ? cr[4*j+2] + bias[nt+ec+4*j+2] : 0.f;
          v.w = act ? cr[4*j+3] + bias[nt+ec+4*j+3] : 0.f;
          reinterpret_cast<float4*>(dst)[j] = v;
        }
      } else {
        #pragma unroll
        for (int j=0;j<16;j++){
          int col = nt + ec + j;
          if (col < N) dst[j] = act ? cr[j] + bias[col] : 0.f;
        }
      }
    }
    __syncthreads();
  }
}

// ---------------------------------------------------------------------------
// Generic bf16 MFMA GEMM (legacy path, kept for the small per-step split-K GEMMs)
// MODE 1: write fp32 partial to outp + blockIdx.z*M*N (split-K, no bias)
// ---------------------------------------------------------------------------
template<int MODE>
__global__ __launch_bounds__(256)
void gemm_bf16(const u16* __restrict__ A, int lda,
               const u16* __restrict__ Bm, int N, int K, int M,
               const float* __restrict__ bias,
               u16* __restrict__ outb,
               float* __restrict__ outp,
               const int* __restrict__ declens)
{
  __shared__ __align__(16) u16 As[64*LDSK];
  __shared__ __align__(16) u16 Bs[64*LDSK];
  __shared__ __align__(16) float Cs[64*68];

  const int tid = threadIdx.x;
  const int nt = blockIdx.x * 64;
  const int mt = blockIdx.y * 64;
  int k0 = 0, k1 = K;
  if (MODE == 1){ int kl = K / KS; k0 = blockIdx.z * kl; k1 = k0 + kl; }

  f32x4 acc[4];
  #pragma unroll
  for (int s = 0; s < 4; s++) acc[s] = f32x4{0.f,0.f,0.f,0.f};

  const int am = tid >> 2;
  const int ak = (tid & 3) * 8;
  const int bk = tid >> 3;
  const int bn = (tid & 7) * 8;
  const int wv = tid >> 6;
  const int ln = tid & 63;
  const int qd = ln >> 4;
  const int lm = ln & 15;

  for (int kc = k0; kc < k1; kc += 32){
    uint4 av = *reinterpret_cast<const uint4*>(A + (size_t)(mt + am) * lda + kc + ak);
    *reinterpret_cast<uint4*>(&As[am * LDSK + ak]) = av;
    u16 bv[8];
    uint4 bq = *reinterpret_cast<const uint4*>(Bm + (size_t)(kc + bk) * N + nt + bn);
    bv[0]=(u16)(bq.x&0xffff); bv[1]=(u16)(bq.x>>16);
    bv[2]=(u16)(bq.y&0xffff); bv[3]=(u16)(bq.y>>16);
    bv[4]=(u16)(bq.z&0xffff); bv[5]=(u16)(bq.z>>16);
    bv[6]=(u16)(bq.w&0xffff); bv[7]=(u16)(bq.w>>16);
    #pragma unroll
    for (int j=0;j<8;j++) Bs[(bn + j) * LDSK + bk] = bv[j];
    __syncthreads();

    s16x8 af = *reinterpret_cast<const s16x8*>(&As[(wv*16 + lm) * LDSK + qd*8]);
    #pragma unroll
    for (int s=0;s<4;s++){
      s16x8 bfr = *reinterpret_cast<const s16x8*>(&Bs[(s*16 + lm) * LDSK + qd*8]);
      acc[s] = __builtin_amdgcn_mfma_f32_16x16x32_bf16(af, bfr, acc[s], 0, 0, 0);
    }
    __syncthreads();
  }

  #pragma unroll
  for (int s=0;s<4;s++)
    #pragma unroll
    for (int r=0;r<4;r++)
      Cs[(wv*16 + qd*4 + r)*68 + s*16 + lm] = acc[s][r];
  __syncthreads();

  const int row = tid >> 2;
  const int cs0 = (tid & 3) * 16;
  if (MODE == 1){
    float* dst = outp + (size_t)blockIdx.z * M * N + (size_t)(mt+row)*N + nt + cs0;
    #pragma unroll
    for (int j=0;j<4;j++){
      float4 v = { Cs[row*68+cs0+4*j], Cs[row*68+cs0+4*j+1],
                   Cs[row*68+cs0+4*j+2], Cs[row*68+cs0+4*j+3] };
      reinterpret_cast<float4*>(dst)[j] = v;
    }
  }
}

// ---------------------------------------------------------------------------
__global__ void cvt_bf16(const float* __restrict__ in, u16* __restrict__ out, int n4){
  int i = blockIdx.x * blockDim.x + threadIdx.x;
  int stride = gridDim.x * blockDim.x;
  for (; i < n4; i += stride){
    float4 v = reinterpret_cast<const float4*>(in)[i];
    __align__(8) u16 p[4] = {f2bf(v.x), f2bf(v.y), f2bf(v.z), f2bf(v.w)};
    reinterpret_cast<uint2*>(out)[i] = *reinterpret_cast<uint2*>(p);
  }
}

// WT[n][k] = f2bf(W[k][n]); n >= N rows written as zero (padding)
__global__ void transpose_cvt(const float* __restrict__ in, u16* __restrict__ out,
                              int K, int N)
{
  __shared__ float tile[32][33];
  int n0 = blockIdx.x * 32, k0 = blockIdx.y * 32;
  int tx = threadIdx.x, ty = threadIdx.y;  // 32 x 8
  #pragma unroll
  for (int j=0;j<4;j++){
    int k = k0 + ty + j*8, n = n0 + tx;
    tile[ty + j*8][tx] = (n < N) ? in[(size_t)k*N + n] : 0.f;
  }
  __syncthreads();
  #pragma unroll
  for (int j=0;j<4;j++){
    int nl = ty + j*8;
    out[(size_t)(n0 + nl)*K + k0 + tx] = f2bf(tile[tx][nl]);
  }
}

// BigB[k][n] (3072 x 2048 bf16): k<2560 -> W_ih[n][k], else W_hh[n][k-2560]
__global__ void build_bigb(const float* __restrict__ Wih, const float* __restrict__ Whh,
                           u16* __restrict__ out)
{
  __shared__ float tile[32][33];
  int k0 = blockIdx.x * 32, n0 = blockIdx.y * 32;
  int tx = threadIdx.x, ty = threadIdx.y;  // 32 x 8
  #pragma unroll
  for (int j=0;j<4;j++){
    int nl = ty + j*8;
    int n = n0 + nl, k = k0 + tx;
    float v = (k0 < 2560) ? Wih[(size_t)n*2560 + k] : Whh[(size_t)n*512 + (k - 2560)];
    tile[nl][tx] = v;
  }
  __syncthreads();
  #pragma unroll
  for (int j=0;j<4;j++){
    int kl = ty + j*8;
    out[(size_t)(k0 + kl)*NGATE + n0 + tx] = f2bf(tile[tx][kl]);
  }
}

// stable descending counting sort + sorted outputs
__global__ void sort_kernel(const int* __restrict__ cap_len, const int* __restrict__ caps,
                            int* __restrict__ sortind, int* __restrict__ declens,
                            int* __restrict__ caps_s,
                            float* __restrict__ out_caps, float* __restrict__ out_declens,
                            float* __restrict__ out_sortind)
{
  __shared__ int si[B_];
  if (threadIdx.x == 0){
    int cnt = 0;
    for (int v = L_; v >= 0 && cnt < B_; v--)
      for (int b = 0; b < B_; b++)
        if (cap_len[b] == v) si[cnt++] = b;
  }
  __syncthreads();
  for (int i = threadIdx.x; i < B_; i += 256){
    int sb = si[i];
    sortind[i] = sb; out_sortind[i] = (float)sb;
    int dl = cap_len[sb] - 1;
    declens[i] = dl; out_declens[i] = (float)dl;
  }
  for (int i = threadIdx.x; i < B_*L_; i += 256){
    int bb = i / L_;
    int c = caps[si[bb]*L_ + (i % L_)];
    caps_s[i] = c; out_caps[i] = (float)c;
  }
}

__global__ void emb_fill(const float* __restrict__ emb_table, const int* __restrict__ caps_i,
                         u16* __restrict__ xa, int t)
{
  int b = blockIdx.x;
  int cap = caps_i[b*L_ + t];
  for (int k = threadIdx.x; k < EMB_; k += 256)
    xa[(size_t)b*KGATE + k] = f2bf(emb_table[(size_t)cap*EMB_ + k]);
}

// per-step: e = relu(attn1 + attn2) . wf + bf ; softmax over P ; write alpha
__global__ __launch_bounds__(256)
void attn_esm(const u16* __restrict__ attn1, const float* __restrict__ a2part,
              const float* __restrict__ bd, const float* __restrict__ wf,
              const float* __restrict__ bfp,
              const int* __restrict__ sortind, const int* __restrict__ declens,
              float* __restrict__ alpha_buf, float* __restrict__ out_alphas, int t)
{
  __shared__ float a2[ATT_];
  __shared__ float wfs[ATT_];
  __shared__ float es[P_];
  __shared__ float red[8];
  int b = blockIdx.x, tid = threadIdx.x;
  for (int i = tid; i < ATT_; i += 256){
    float v = bd[i];
    #pragma unroll
    for (int s=0;s<KS;s++) v += a2part[((size_t)s*B_ + b)*ATT_ + i];
    a2[i] = v;
    wfs[i] = wf[i];
  }
  __syncthreads();
  int sb = sortind[b];
  const u16* arow = attn1 + (size_t)sb * P_ * ATT_;
  int wv = tid >> 6, ln = tid & 63;
  float bfv = bfp[0];
  for (int i = 0; i < P_/4; i++){
    int p = i*4 + wv;
    uint4 q = *reinterpret_cast<const uint4*>(arow + (size_t)p*ATT_ + ln*8);
    u32 wd_[4] = {q.x, q.y, q.z, q.w};
    float sum = 0.f;
    #pragma unroll
    for (int j=0;j<4;j++){
      int a0 = ln*8 + 2*j;
      float v0 = bf2f((u16)(wd_[j] & 0xffff)) + a2[a0];
      float v1 = bf2f((u16)(wd_[j] >> 16))    + a2[a0+1];
      sum += fmaxf(v0, 0.f) * wfs[a0];
      sum += fmaxf(v1, 0.f) * wfs[a0+1];
    }
    #pragma unroll
    for (int off=32; off; off>>=1) sum += __shfl_xor(sum, off);
    if (ln == 0) es[p] = sum + bfv;
  }
  __syncthreads();
  float m = (tid < P_) ? es[tid] : -1e30f;
  #pragma unroll
  for (int off=32; off; off>>=1) m = fmaxf(m, __shfl_xor(m, off));
  if (ln == 0) red[wv] = m;
  __syncthreads();
  m = fmaxf(fmaxf(red[0],red[1]), fmaxf(red[2],red[3]));
  float ev = (tid < P_) ? expf(es[tid] - m) : 0.f;
  float sm = ev;
  #pragma unroll
  for (int off=32; off; off>>=1) sm += __shfl_xor(sm, off);
  if (ln == 0) red[4+wv] = sm;
  __syncthreads();
  float tot = red[4]+red[5]+red[6]+red[7];
  if (tid < P_){
    float al = ev / tot;
    alpha_buf[b*P_ + tid] = al;
    out_alphas[((size_t)b*T_ + t)*P_ + tid] = (t < declens[b]) ? al : 0.f;
  }
}

// ctx[b, :] = sum_p alpha[b,p] * enc[sb, p, :]; writes bf16 into xa ctx slot
__global__ __launch_bounds__(256)
void ctx_kernel(const u16* __restrict__ enc_bf, const float* __restrict__ alpha_buf,
                const int* __restrict__ sortind, u16* __restrict__ xa)
{
  __shared__ float al[P_];
  int b = blockIdx.x, ch = blockIdx.y, tid = threadIdx.x;
  for (int i = tid; i < P_; i += 256) al[i] = alpha_buf[b*P_ + i];
  __syncthreads();
  int sb = sortind[b];
  const u16* eb = enc_bf + (size_t)sb * P_ * ENC_ + ch * 1024 + tid * 4;
  float a0=0.f, a1=0.f, a2v=0.f, a3=0.f;
  #pragma unroll 4
  for (int p=0;p<P_;p++){
    uint2 q = *reinterpret_cast<const uint2*>(eb + (size_t)p * ENC_);
    float w = al[p];
    a0  += w * bf2f((u16)(q.x & 0xffff));
    a1  += w * bf2f((u16)(q.x >> 16));
    a2v += w * bf2f((u16)(q.y & 0xffff));
    a3  += w * bf2f((u16)(q.y >> 16));
  }
  __align__(8) u16 pk[4] = {f2bf(a0), f2bf(a1), f2bf(a2v), f2bf(a3)};
  *reinterpret_cast<uint2*>(xa + (size_t)b*KGATE + EMB_ + ch*1024 + tid*4) =
      *reinterpret_cast<uint2*>(pk);
}

// LSTM cell + history store + next-step embedding gather
__global__ __launch_bounds__(256)
void lstm_kernel(const float* __restrict__ gpart, const float* __restrict__ bih,
                 const float* __restrict__ bhh,
                 float* __restrict__ hf, float* __restrict__ cfb,
                 u16* __restrict__ xa, u16* __restrict__ Hh,
                 const int* __restrict__ declens, const int* __restrict__ caps_i,
                 const float* __restrict__ emb_table, int t)
{
  int b = blockIdx.x, tid = threadIdx.x;
  bool act = t < declens[b];
  #pragma unroll
  for (int j=0;j<2;j++){
    int n = j*256 + tid;   // 0..511
    float gi = bih[n]      + bhh[n];
    float gf = bih[n+512]  + bhh[n+512];
    float gg = bih[n+1024] + bhh[n+1024];
    float go = bih[n+1536] + bhh[n+1536];
    #pragma unroll
    for (int s=0;s<KS;s++){
      const float* gp = gpart + ((size_t)s*B_ + b)*NGATE;
      gi += gp[n]; gf += gp[n+512]; gg += gp[n+1024]; go += gp[n+1536];
    }
    float co = cfb[b*DEC_ + n];
    float iv = 1.f/(1.f + expf(-gi));
    float fv = 1.f/(1.f + expf(-gf));
    float gv = tanhf(gg);
    float ov = 1.f/(1.f + expf(-go));
    float cn = fv*co + iv*gv;
    float hn = ov * tanhf(cn);
    float ho = act ? hn : hf[b*DEC_ + n];
    float c2 = act ? cn : co;
    hf[b*DEC_ + n] = ho;
    cfb[b*DEC_ + n] = c2;
    u16 hb = f2bf(ho);
    xa[(size_t)b*KGATE + EMB_ + ENC_ + n] = hb;
    Hh[((size_t)t*B_ + b)*DEC_ + n] = hb;
  }
  if (t + 1 < T_){
    int cap = caps_i[b*L_ + t + 1];
    for (int k = tid; k < EMB_; k += 256)
      xa[(size_t)b*KGATE + k] = f2bf(emb_table[(size_t)cap*EMB_ + k]);
  }
}

// ---------------------------------------------------------------------------
extern "C" void kernel_launch(void* const* d_in, const int* in_sizes, int n_in,
                              void* d_out, int out_size, void* d_ws, size_t ws_size,
                              hipStream_t stream)
{
  (void)in_sizes; (void)n_in; (void)out_size; (void)ws_size;
  const float* enc  = (const float*)d_in[0];
  const int*   caps = (const int*)d_in[1];
  const int*   clen = (const int*)d_in[2];
  const float* embt = (const float*)d_in[3];
  const float* We   = (const float*)d_in[4];
  const float* be   = (const float*)d_in[5];
  const float* Wd   = (const float*)d_in[6];
  const float* bd   = (const float*)d_in[7];
  const float* wf   = (const float*)d_in[8];
  const float* bfp  = (const float*)d_in[9];
  const float* Wih  = (const float*)d_in[10];
  const float* bih  = (const float*)d_in[11];
  const float* Whh  = (const float*)d_in[12];
  const float* bhh  = (const float*)d_in[13];
  const float* Wfc  = (const float*)d_in[14];
  const float* bfc  = (const float*)d_in[15];

  float* out = (float*)d_out;
  float* out_outputs = out;
  float* out_caps    = out + (size_t)80640000;
  float* out_declens = out + (size_t)80640000 + 2816;
  float* out_alphas  = out + (size_t)80640000 + 2816 + 128;
  float* out_sortind = out + (size_t)80640000 + 2816 + 128 + 526848;

  char* w = (char*)d_ws;
  size_t off = 0;
  auto alloc = [&](size_t bytes)->char*{
    char* p = w + off; off += (bytes + 255) & ~(size_t)255; return p;
  };
  u16*  enc_bf = (u16*)alloc((size_t)B_*P_*ENC_*2);
  u16*  attn1  = (u16*)alloc((size_t)B_*P_*ATT_*2);
  u16*  WeT    = (u16*)alloc((size_t)ATT_*ENC_*2);      // We^T (512 x 2048)
  u16*  Wd_bf  = (u16*)alloc((size_t)DEC_*ATT_*2);
  u16*  BigB   = (u16*)alloc((size_t)KGATE*NGATE*2);
  u16*  WfcT   = (u16*)alloc((size_t)VPAD_*DEC_*2);     // Wfc^T (30080 x 512, pad-zeroed)
  u16*  Hh     = (u16*)alloc((size_t)T_*B_*DEC_*2);
  float* hf    = (float*)alloc((size_t)B_*DEC_*4);    // | contiguous zero region
  float* cf    = (float*)alloc((size_t)B_*DEC_*4);    // |
  u16*  xa     = (u16*)alloc((size_t)B_*KGATE*2);     // | [emb | ctx | h] bf16
  float* a2p   = (float*)alloc((size_t)KS*B_*ATT_*4);
  float* gp    = (float*)alloc((size_t)KS*B_*NGATE*4);
  float* albuf = (float*)alloc((size_t)B_*P_*4);
  int*  caps_i = (int*)alloc((size_t)B_*L_*4);
  int*  decl_i = (int*)alloc(512);
  int*  sort_i = (int*)alloc(512);

  // zero h, c, xa (one contiguous memset; all sub-blocks are 256B-aligned sizes)
  hipMemsetAsync(hf, 0, (size_t)B_*DEC_*4*2 + (size_t)B_*KGATE*2, stream);

  sort_kernel<<<1, 256, 0, stream>>>(clen, caps, sort_i, decl_i, caps_i,
                                     out_caps, out_declens, out_sortind);
  emb_fill<<<B_, 256, 0, stream>>>(embt, caps_i, xa, 0);

  cvt_bf16<<<4096, 256, 0, stream>>>(enc, enc_bf, (int)((size_t)B_*P_*ENC_/4));
  cvt_bf16<<<128, 256, 0, stream>>>(Wd, Wd_bf, DEC_*ATT_/4);
  transpose_cvt<<<dim3(ATT_/32, ENC_/32), dim3(32, 8), 0, stream>>>(We, WeT, ENC_, ATT_);
  transpose_cvt<<<dim3(VPAD_/32, DEC_/32), dim3(32, 8), 0, stream>>>(Wfc, WfcT, DEC_, V_);
  build_bigb<<<dim3(KGATE/32, NGATE/32), dim3(32, 8), 0, stream>>>(Wih, Whh, BigB);

  // attn1 = enc @ We + be  (M=25088, K=2048, N=512), bf16 out
  gemm_bt<0><<<dim3(ATT_/128, (B_*P_)/128), 256, 0, stream>>>(
      enc_bf, WeT, ATT_, ENC_, be, attn1, nullptr, nullptr);

  for (int t = 0; t < T_; t++){
    // attn2 partials: h @ Wd  (M=128, K=512, N=512), split-K
    gemm_bf16<1><<<dim3(ATT_/64, B_/64, KS), 256, 0, stream>>>(
        xa + EMB_ + ENC_, KGATE, Wd_bf, ATT_, DEC_, B_, nullptr, nullptr, a2p, nullptr);
    attn_esm<<<B_, 256, 0, stream>>>(attn1, a2p, bd, wf, bfp, sort_i, decl_i,
                                     albuf, out_alphas, t);
    ctx_kernel<<<dim3(B_, 2), 256, 0, stream>>>(enc_bf, albuf, sort_i, xa);
    // gates partials: [emb|ctx|h] @ BigB  (M=128, K=3072, N=2048), split-K
    gemm_bf16<1><<<dim3(NGATE/64, B_/64, KS), 256, 0, stream>>>(
        xa, KGATE, BigB, NGATE, KGATE, B_, nullptr, nullptr, gp, nullptr);
    lstm_kernel<<<B_, 256, 0, stream>>>(gp, bih, bhh, hf, cf, xa, Hh,
                                        decl_i, caps_i, embt, t);
  }

  // outputs = mask(Hh @ Wfc + bfc)  (M=2688, K=512, N=30000), M-major grid
  gemm_bt<2><<<dim3((T_*B_)/128, VPAD_/128), 256, 0, stream>>>(
      Hh, WfcT, V_, DEC_, bfc, nullptr, out_outputs, decl_i);
}